// Round 1
// baseline (300.697 us; speedup 1.0000x reference)
//
#include <hip/hip_runtime.h>
#include <hip/hip_bf16.h>

// out[i0,i2,i1] = sum_r f0[i0,r]*f2[i2,r]*f1[i1,r]; N0=512,N1=512,N2=256,R=32.
// GEMM view: out[p, i1] = G[p,:] . f1[i1,:]^T, G = KR(f0,f2), M=131072, N=512, K=32.
//
// R5 (this round): operand-swapped MFMA, direct stores, zero LDS.
//   Previous version (293.8 us bench = ~162 us poison fill + ~132 us kernel) used
//   A=G, B=f1 -> D rows = p -> lane's floatx4 strided 512 in output -> forced
//   LDS transpose (32 ds_write + barrier + 8 ds_read per lane), 33 KB LDS,
//   4 blocks/CU. Kernel wrote 268 MB at only 2.0 TB/s vs 6.5 TB/s proven by the
//   poison fill on the same buffer.
//   A and B fragments of mfma_f32_16x16x32_bf16 share the same per-lane layout
//   (row = lane&15, k = (lane>>4)*8+j; proven by R2==R3 bit-identical history),
//   so swapping operands gives D[m=i1_local][n=p_col] (col=lane&15, row=q*4+v,
//   m89-verified). Lane's floatx4 = 4 CONSECUTIVE i1 floats of one output row ->
//   store straight from the accumulator. No LDS, no barrier, ~50 fewer
//   instructions/lane, 8 blocks/CU.
// Floor: 268 MB fp32 out / 6.5 TB/s (fill-measured) = ~41 us for the kernel.

#define N0 512
#define N1 512
#define N2 256
#define R  32

typedef __bf16  bf16x8  __attribute__((ext_vector_type(8)));
typedef float   floatx4 __attribute__((ext_vector_type(4)));

__global__ __launch_bounds__(256, 8)
void cp_mfma_kernel(const float* __restrict__ f0,
                    const float* __restrict__ f1,
                    const float* __restrict__ f2,
                    float* __restrict__ out) {
    const int tid  = threadIdx.x;
    const int wave = tid >> 6;
    const int lane = tid & 63;
    const int n    = lane & 15;   // B: p-col index; A: i1-row index
    const int q    = lane >> 4;   // quad -> k = q*8 + j

    const int blk     = blockIdx.x;
    const int i0      = blk >> 4;
    const int i2_base = (blk & 15) << 4;
    const long p_base = (long)blk * 16;

    // ---- B operand (G fragment): B[k=q*8+j][n] = bf16( f0[i0][k] * f2[i2_base+n][k] )
    bf16x8 g;
    {
        const floatx4 v0a = *(const floatx4*)(f0 + i0 * R + q * 8);
        const floatx4 v0b = *(const floatx4*)(f0 + i0 * R + q * 8 + 4);
        const floatx4 v2a = *(const floatx4*)(f2 + (i2_base + n) * R + q * 8);
        const floatx4 v2b = *(const floatx4*)(f2 + (i2_base + n) * R + q * 8 + 4);
        #pragma unroll
        for (int j = 0; j < 4; ++j) {
            g[j]     = (__bf16)(v0a[j] * v2a[j]);
            g[j + 4] = (__bf16)(v0b[j] * v2b[j]);
        }
    }

    // ---- wave covers i1 cols [wave*128, +128): 8 MFMAs, store direct from acc.
    // Lane (n,q) owns out[(p_base+n)][colbase + t*16 + q*4 .. +3]:
    //   q groups 0..3 of a given n are 16B-contiguous -> 64B chunks per row per
    //   instruction; t and t+1 fill the two halves of each 128B line back-to-back.
    const int colbase = wave * 128;
    float* const outp = out + (p_base + n) * (long)N1 + colbase + q * 4;

    #pragma unroll
    for (int t = 0; t < 8; ++t) {
        // A operand (f1 fragment): A[m=n][k=q*8+j] = bf16( f1[colbase+t*16+m][k] )
        const float* f1p = f1 + (colbase + t * 16 + n) * R + q * 8;
        const floatx4 ba = *(const floatx4*)(f1p);
        const floatx4 bb = *(const floatx4*)(f1p + 4);
        bf16x8 a;
        #pragma unroll
        for (int j = 0; j < 4; ++j) {
            a[j]     = (__bf16)ba[j];
            a[j + 4] = (__bf16)bb[j];
        }
        floatx4 c = {0.f, 0.f, 0.f, 0.f};
        // Swapped operands vs R4: D[m=i1_local][n=p_col].
        const floatx4 d = __builtin_amdgcn_mfma_f32_16x16x32_bf16(a, g, c, 0, 0, 0);
        *(floatx4*)(outp + t * 16) = d;
    }
}

extern "C" void kernel_launch(void* const* d_in, const int* in_sizes, int n_in,
                              void* d_out, int out_size, void* d_ws, size_t ws_size,
                              hipStream_t stream) {
    const float* f0 = (const float*)d_in[0];
    const float* f1 = (const float*)d_in[1];
    const float* f2 = (const float*)d_in[2];
    float* out = (float*)d_out;

    const int n_blocks = (N0 * N2) / 16;  // 8192 blocks x 256 threads
    cp_mfma_kernel<<<dim3(n_blocks), dim3(256), 0, stream>>>(f0, f1, f2, out);
}